// Round 12
// baseline (168.345 us; speedup 1.0000x reference)
//
#include <hip/hip_runtime.h>

#define NB 32
#define WAVES_PER_BLOCK 4
#define TOKENS_PER_WAVE 4

__device__ __forceinline__ float clamp01(float x) {
    return fminf(fmaxf(x, 0.0f), 1.0f);
}

// Async global->LDS DMA (gfx950): lane copies `size` bytes from its own
// global address to wave-uniform LDS base + lane*size. Zero VGPR cost,
// cannot be sunk/spilled like a register prefetch (r6/r9 failure mode).
__device__ __forceinline__ void gload_lds16(const float* g, float* lds) {
    __builtin_amdgcn_global_load_lds(
        (const __attribute__((address_space(1))) void*)g,
        (__attribute__((address_space(3))) void*)lds, 16, 0, 0);
}
__device__ __forceinline__ void gload_lds4(const float* g, float* lds) {
    __builtin_amdgcn_global_load_lds(
        (const __attribute__((address_space(1))) void*)g,
        (__attribute__((address_space(3))) void*)lds, 4, 0, 0);
}

// sigma-swizzled W layout in LDS: 16B chunk c (c = 0..255) holds
// W[i][4*j0 .. 4*j0+3] with j0 = c>>5 and i = ((c&31) - 5*j0) & 31
// (i.e. chunk index for (i,j0) is c = j0*32 + ((i + 5*j0) & 31)).
// The odd multiplier spreads pass-1's per-(i)-row b128 reads of both wave
// halves across all 8 LDS bank-quads (~4-way, vs 32-way for linear
// row-major). DMA stays legal because only the GLOBAL source address is
// permuted (per-lane), LDS dest is linear (guide m173 pattern).

// One wave per token-stream; 4 waves/block; 4 sequential tokens per wave.
// Per token: W(t) is already in LDS (DMA'd one token ago) and its lines sit
// in XCD-local L2, so the pass-2 register copy (m-layout loads) is an L2
// hit issued at pass-1 top. After pass-1's LDS reads, W(t+1)'s DMA is
// issued into the SAME buffer (pass 2 reads only registers + s_hnew),
// covered by pass-2 compute+stores. 1024 blocks -> all waves resident
// from dispatch 0; steady state keeps ~4KB DMA in flight per wave.
__global__ __launch_bounds__(256, 6) void biotoken_step(
    const float* __restrict__ h,
    const float* __restrict__ W,
    const float* __restrict__ stim,
    float* __restrict__ out_h,
    float* __restrict__ out_W)
{
    const int lw   = threadIdx.x & 63;    // lane in wave
    const int wave = threadIdx.x >> 6;    // 0..3
    const int tok0 = (blockIdx.x * WAVES_PER_BLOCK + wave) * TOKENS_PER_WAVE;
    const int i    = lw & 31;             // row this lane owns in pass 1
    const int half = lw >> 5;             // column-half selector

    __shared__ float s_W   [WAVES_PER_BLOCK][NB * NB];   // 4KB, sigma-swizzled
    __shared__ float s_hin [WAVES_PER_BLOCK][NB * 4];    // 512B
    __shared__ float s_hnew[WAVES_PER_BLOCK][NB * 4];    // 512B

    float* bufW = s_W[wave];
    float* bufH = s_hin[wave];
    float* bufN = s_hnew[wave];

    // ---- DMA stage for one token: W (swizzled source) + h (linear) ----
    auto stage = [&](int token) {
        const float* Wt = W + (size_t)token * (NB * NB);
        #pragma unroll
        for (int k = 0; k < 4; ++k) {
            const int c  = k * 64 + lw;            // chunk this lane writes
            const int j0 = c >> 5;
            const int ii = ((c & 31) - 5 * j0) & 31;
            gload_lds16(Wt + ii * NB + 4 * j0, bufW + k * 256);
        }
        const float* ht = h + (size_t)token * (NB * 4);
        gload_lds4(ht + lw,      bufH);            // floats 0..63
        gload_lds4(ht + 64 + lw, bufH + 64);       // floats 64..127
    };

    // ---- prologue ----
    stage(tok0);
    float stiC = stim[(size_t)tok0 * NB + i];      // 128B broadcast
    float stiN = 0.0f;

    #pragma unroll
    for (int tt = 0; tt < TOKENS_PER_WAVE; ++tt) {
        const int token = tok0 + tt;

        __syncthreads();   // vmcnt(0): DMA for THIS token has landed

        // pass-2 register copy of W (m-layout, coalesced): L2 hit — the DMA
        // pulled these exact lines one token ago. Live only within this token.
        const float4* Wt4 = (const float4*)(W + (size_t)token * (NB * NB));
        float4 wr[4];
        wr[0] = Wt4[0 * 64 + lw];
        wr[1] = Wt4[1 * 64 + lw];
        wr[2] = Wt4[2 * 64 + lw];
        wr[3] = Wt4[3 * 64 + lw];

        // ---- pass 1: inflow. lane (i, half) covers j = half*16 .. +15 ----
        float4 wv[4];                      // lane's 4 swizzled row-chunks
        #pragma unroll
        for (int q = 0; q < 4; ++q) {
            const int j0v = half * 4 + q;
            const int cc  = j0v * 32 + ((i + 5 * j0v) & 31);
            wv[q] = *(const float4*)&bufW[4 * cc];
        }

        float accE = 0.f, accP = 0.f, accG = 0.f, accL = 0.f, tot = 0.f;
        #pragma unroll
        for (int q = 0; q < 4; ++q) {
            const float* wp = (const float*)&wv[q];
            #pragma unroll
            for (int dj = 0; dj < 4; ++dj) {
                const int j = half * 16 + 4 * q + dj;   // same order as champion
                float w = wp[dj];
                w = (j == i) ? 0.0f : w;                // zero self-connection
                const float4 hj = *(const float4*)&bufH[j * 4];  // broadcast
                accE = fmaf(w, hj.x, accE);
                accP = fmaf(w, hj.y, accP);
                accG = fmaf(w, hj.z, accG);
                accL = fmaf(w, hj.w, accL);
                tot += w;
            }
        }
        accE += __shfl_xor(accE, 32);
        accP += __shfl_xor(accP, 32);
        accG += __shfl_xor(accG, 32);
        accL += __shfl_xor(accL, 32);
        tot  += __shfl_xor(tot,  32);

        const float inv = 1.0f / (tot + 1e-8f);
        const float En = accE * inv, Pn = accP * inv;
        const float Gn = accG * inv, Ln = accL * inv;

        // ---- EPGL state update (redundant across halves) ----
        const float4 hi = *(const float4*)&bufH[i * 4];
        const float E = hi.x, P = hi.y, G = hi.z, L = hi.w;

        const float E_new = clamp01(E + 0.3f * stiC - 0.4f * P - 0.2f * G);
        const float P_new = clamp01(P + 0.5f * stiC + 0.3f * (Pn - P) - 0.2f * E);
        const float G_new = clamp01(G + 0.4f * E * (1.0f - P) + 0.2f * (Gn - G) - 0.3f * P);
        const float good  = 0.5f * En + 0.5f * Gn;
        const float L_new = clamp01(L + 0.4f * good + 0.3f * (Ln - L) - 0.3f * P);

        if (half == 0) {
            const float4 hn = make_float4(E_new, P_new, G_new, L_new);
            ((float4*)bufN)[i] = hn;
            ((float4*)(out_h + (size_t)token * (NB * 4)))[i] = hn;
        }

        // ---- all LDS W/h reads for token t are done: DMA token t+1 ----
        __builtin_amdgcn_sched_barrier(0);   // pin: no motion across this point
        if (tt + 1 < TOKENS_PER_WAVE) {
            stage(token + 1);
            stiN = stim[(size_t)(token + 1) * NB + i];
        }
        __builtin_amdgcn_sched_barrier(0);

        // ---- pass 2: W_new from wr registers + bufN (wave-private) ----
        float4* outWt = (float4*)(out_W + (size_t)token * (NB * NB));
        const int jb0 = (lw & 7) * 4;      // hj cols depend only on lw&7
        float4 hjv[4];
        #pragma unroll
        for (int e = 0; e < 4; ++e) {
            hjv[e] = *(const float4*)&bufN[(jb0 + e) * 4];
        }

        #pragma unroll
        for (int k = 0; k < 4; ++k) {
            const int m = k * 64 + lw;     // float4 index in token's W
            const int r = m >> 3;          // row
            const float4 hr = *(const float4*)&bufN[r * 4];
            const float  Lr = hr.w;
            const float* wp = (const float*)&wr[k];
            float4 res;
            float* resp = &res.x;
            #pragma unroll
            for (int e = 0; e < 4; ++e) {
                const int j = jb0 + e;
                const float4 hj = hjv[e];
                const float dx = hr.x - hj.x;
                const float dy = hr.y - hj.y;
                const float dz = hr.z - hj.z;
                const float dw = hr.w - hj.w;
                const float sq = dx * dx + dy * dy + dz * dz + dw * dw;
                const float dist = sqrtf(sq);             // sqrt(0)=0 matches ref
                const float mutual = 0.5f * (Lr + hj.w);
                float wn = 0.95f * wp[e] + 0.1f * mutual * dist;
                wn = clamp01(wn);
                resp[e] = (j == r) ? 0.0f : wn;           // zero diagonal
            }
            outWt[m] = res;                // coalesced 1KB/instr store
        }

        stiC = stiN;
    }
}

extern "C" void kernel_launch(void* const* d_in, const int* in_sizes, int n_in,
                              void* d_out, int out_size, void* d_ws, size_t ws_size,
                              hipStream_t stream) {
    const float* h    = (const float*)d_in[0];  // [8,2048,32,4]
    const float* W    = (const float*)d_in[1];  // [8,2048,32,32]
    const float* stim = (const float*)d_in[2];  // [8,2048,32]

    const int tokens = in_sizes[2] / NB;        // 16384
    float* out_h = (float*)d_out;               // [8,2048,32,4]
    float* out_W = (float*)d_out + (size_t)tokens * NB * 4;  // [8,2048,32,32]

    const int blocks = tokens / (WAVES_PER_BLOCK * TOKENS_PER_WAVE); // 1024
    biotoken_step<<<blocks, 256, 0, stream>>>(h, W, stim, out_h, out_W);
}